// Round 1
// baseline (1315.615 us; speedup 1.0000x reference)
//
#include <hip/hip_runtime.h>
#include <hip/hip_bf16.h>

// Problem constants (fixed by setup_inputs)
#define Bb   16
#define Cc   384
#define Nn   1024      // H*W = 32*32
#define NH   8
#define HD   48        // Cc / NH
#define C3   1152      // 3*Cc
#define QSZ  (Bb*NH*Nn*HD)   // 6,291,456 floats per q/k/v tensor

// ---------------------------------------------------------------------------
// Kernel 1: QKV GEMM.  qkv[b][j][n] = sum_c qkv_w[j][c] * x[b][c][n] + qkv_b[j]
// Output scattered to q/k/v buffers laid out [B][NH][N][HD].
// Tile: 64(j) x 64(n), K-chunk 16, 16x16 threads, 4x4 per thread.
// ---------------------------------------------------------------------------
__global__ __launch_bounds__(256) void qkv_kernel(
    const float* __restrict__ x, const float* __restrict__ w,
    const float* __restrict__ bias,
    float* __restrict__ qb, float* __restrict__ kb, float* __restrict__ vb) {
  __shared__ float Wt[16][68];   // [c][j]  (transposed, padded)
  __shared__ float Xs[16][64];   // [c][n]
  const int b  = blockIdx.z;
  const int j0 = blockIdx.y * 64;
  const int n0 = blockIdx.x * 64;
  const int tid = threadIdx.x;
  const int tx = tid & 15, ty = tid >> 4;
  const float* xb = x + (size_t)b * Cc * Nn;

  float acc[4][4] = {};
  for (int c0 = 0; c0 < Cc; c0 += 16) {
    {  // W tile: 64 rows(j) x 16 cols(c), store transposed
      int r = tid >> 2, c4 = (tid & 3) * 4;
      float4 wv = *(const float4*)(w + (size_t)(j0 + r) * Cc + c0 + c4);
      Wt[c4 + 0][r] = wv.x; Wt[c4 + 1][r] = wv.y;
      Wt[c4 + 2][r] = wv.z; Wt[c4 + 3][r] = wv.w;
    }
    {  // X tile: 16 rows(c) x 64 cols(n), already k-major
      int r = tid >> 4, n4 = (tid & 15) * 4;
      *(float4*)&Xs[r][n4] = *(const float4*)(xb + (size_t)(c0 + r) * Nn + n0 + n4);
    }
    __syncthreads();
#pragma unroll
    for (int kk = 0; kk < 16; kk++) {
      float4 wv = *(const float4*)&Wt[kk][ty * 4];
      float4 xv = *(const float4*)&Xs[kk][tx * 4];
      acc[0][0] += wv.x * xv.x; acc[0][1] += wv.x * xv.y; acc[0][2] += wv.x * xv.z; acc[0][3] += wv.x * xv.w;
      acc[1][0] += wv.y * xv.x; acc[1][1] += wv.y * xv.y; acc[1][2] += wv.y * xv.z; acc[1][3] += wv.y * xv.w;
      acc[2][0] += wv.z * xv.x; acc[2][1] += wv.z * xv.y; acc[2][2] += wv.z * xv.z; acc[2][3] += wv.z * xv.w;
      acc[3][0] += wv.w * xv.x; acc[3][1] += wv.w * xv.y; acc[3][2] += wv.w * xv.z; acc[3][3] += wv.w * xv.w;
    }
    __syncthreads();
  }

  // Scatter-store with head split. 4 consecutive j never cross a 48-boundary.
  const int jg0  = j0 + ty * 4;
  const int part = jg0 / Cc;
  const int rem  = jg0 % Cc;
  const int h    = rem / HD;
  const int d    = rem % HD;
  float4 bv = *(const float4*)(bias + jg0);
  float* dst = (part == 0) ? qb : (part == 1) ? kb : vb;
  float* base = dst + (((size_t)b * NH + h) * Nn) * HD + d;
#pragma unroll
  for (int jj = 0; jj < 4; jj++) {
    int n = n0 + tx * 4 + jj;
    float4 val;
    val.x = acc[0][jj] + bv.x; val.y = acc[1][jj] + bv.y;
    val.z = acc[2][jj] + bv.z; val.w = acc[3][jj] + bv.w;
    *(float4*)(base + (size_t)n * HD) = val;
  }
}

// ---------------------------------------------------------------------------
// Kernel 2: L2-normalize rows of q and k (row = 48 floats). 16 threads/row.
// ---------------------------------------------------------------------------
__global__ __launch_bounds__(256) void norm_kernel(float* __restrict__ qb,
                                                   float* __restrict__ kb) {
  const int tid = threadIdx.x;
  const int row = blockIdx.x * 16 + (tid >> 4);
  const int l16 = tid & 15;
  const int TOT = Bb * NH * Nn;   // rows per tensor
  float* buf = (row < TOT) ? qb : kb;
  int r = (row < TOT) ? row : row - TOT;
  float* p = buf + (size_t)r * HD + l16 * 3;
  float a = p[0], b = p[1], c = p[2];
  float ss = a * a + b * b + c * c;
  ss += __shfl_xor(ss, 1, 16);
  ss += __shfl_xor(ss, 2, 16);
  ss += __shfl_xor(ss, 4, 16);
  ss += __shfl_xor(ss, 8, 16);
  float scale = 1.0f / fmaxf(sqrtf(ss), 1e-12f);
  p[0] = a * scale; p[1] = b * scale; p[2] = c * scale;
}

// ---------------------------------------------------------------------------
// Kernel 3: streaming softmax attention.  One lane = one q row.
// q,k normalized => |q.k| <= 1 => logit bound M = |T|: static softmax max,
// no online rescale.  k/v tiles (64 x 48) staged in LDS; all lanes read the
// same k/v element simultaneously => LDS broadcast.
// out[b][n][h*48+d] = sum_m softmax_m(q_n.k_m * T) * v[m][d]
// ---------------------------------------------------------------------------
__global__ __launch_bounds__(128) void attn_kernel(
    const float* __restrict__ qb, const float* __restrict__ kb,
    const float* __restrict__ vb, const float* __restrict__ temp,
    float* __restrict__ ob) {
  __shared__ float kt[64 * HD];
  __shared__ float vt[64 * HD];
  const int b = blockIdx.z, h = blockIdx.y;
  const int qrow = blockIdx.x * 128 + threadIdx.x;
  const int tid = threadIdx.x;
  const size_t headbase = (((size_t)b * NH + h) * Nn) * HD;

  float qr[HD];
  {
    const float* qp = qb + headbase + (size_t)qrow * HD;
#pragma unroll
    for (int i = 0; i < 12; i++) {
      float4 v = *(const float4*)(qp + i * 4);
      qr[i * 4 + 0] = v.x; qr[i * 4 + 1] = v.y;
      qr[i * 4 + 2] = v.z; qr[i * 4 + 3] = v.w;
    }
  }
  const float T = temp[h];
  const float M = fabsf(T);   // static bound on |s*T|
  float oacc[HD] = {};
  float lsum = 0.0f;
  const float4* kg_base = (const float4*)(kb + headbase);
  const float4* vg_base = (const float4*)(vb + headbase);
  float4* kt4 = (float4*)kt;
  float4* vt4 = (float4*)vt;

  for (int m0 = 0; m0 < Nn; m0 += 64) {
    __syncthreads();
    const float4* kg = kg_base + (size_t)m0 * (HD / 4);
    const float4* vg = vg_base + (size_t)m0 * (HD / 4);
    for (int idx = tid; idx < 64 * HD / 4; idx += 128) {
      kt4[idx] = kg[idx];
      vt4[idx] = vg[idx];
    }
    __syncthreads();
    for (int mm = 0; mm < 64; mm++) {
      const float* kr = kt + mm * HD;
      float s = 0.0f;
#pragma unroll
      for (int i = 0; i < 12; i++) {
        float4 kv = *(const float4*)(kr + i * 4);
        s += qr[i * 4 + 0] * kv.x + qr[i * 4 + 1] * kv.y +
             qr[i * 4 + 2] * kv.z + qr[i * 4 + 3] * kv.w;
      }
      float p = __expf(s * T - M);
      lsum += p;
      const float* vr = vt + mm * HD;
#pragma unroll
      for (int i = 0; i < 12; i++) {
        float4 vv = *(const float4*)(vr + i * 4);
        oacc[i * 4 + 0] += p * vv.x; oacc[i * 4 + 1] += p * vv.y;
        oacc[i * 4 + 2] += p * vv.z; oacc[i * 4 + 3] += p * vv.w;
      }
    }
  }
  const float inv = 1.0f / lsum;
  float* op = ob + ((size_t)b * Nn + qrow) * Cc + h * HD;
#pragma unroll
  for (int i = 0; i < 12; i++) {
    float4 v;
    v.x = oacc[i * 4 + 0] * inv; v.y = oacc[i * 4 + 1] * inv;
    v.z = oacc[i * 4 + 2] * inv; v.w = oacc[i * 4 + 3] * inv;
    *(float4*)(op + i * 4) = v;
  }
}

// ---------------------------------------------------------------------------
// Kernel 4: output projection.
// out[b][c][n] = sum_j ob[b][n][j] * proj_w[c][j] + proj_b[c]
// Tile 64(c) x 64(n), K-chunk 16; both operands transposed into k-major LDS.
// ---------------------------------------------------------------------------
__global__ __launch_bounds__(256) void proj_kernel(
    const float* __restrict__ ob, const float* __restrict__ pw,
    const float* __restrict__ pb, float* __restrict__ out) {
  __shared__ float Pt[16][68];   // [j][c]
  __shared__ float At[16][68];   // [j][n]
  const int b  = blockIdx.z;
  const int c0 = blockIdx.y * 64;
  const int n0 = blockIdx.x * 64;
  const int tid = threadIdx.x;
  const int tx = tid & 15, ty = tid >> 4;

  float acc[4][4] = {};
  for (int j0 = 0; j0 < Cc; j0 += 16) {
    int r = tid >> 2, j4 = (tid & 3) * 4;
    {
      float4 pv = *(const float4*)(pw + (size_t)(c0 + r) * Cc + j0 + j4);
      Pt[j4 + 0][r] = pv.x; Pt[j4 + 1][r] = pv.y;
      Pt[j4 + 2][r] = pv.z; Pt[j4 + 3][r] = pv.w;
    }
    {
      float4 av = *(const float4*)(ob + ((size_t)b * Nn + n0 + r) * Cc + j0 + j4);
      At[j4 + 0][r] = av.x; At[j4 + 1][r] = av.y;
      At[j4 + 2][r] = av.z; At[j4 + 3][r] = av.w;
    }
    __syncthreads();
#pragma unroll
    for (int kk = 0; kk < 16; kk++) {
      float4 cv = *(const float4*)&Pt[kk][ty * 4];
      float4 nv = *(const float4*)&At[kk][tx * 4];
      acc[0][0] += cv.x * nv.x; acc[0][1] += cv.x * nv.y; acc[0][2] += cv.x * nv.z; acc[0][3] += cv.x * nv.w;
      acc[1][0] += cv.y * nv.x; acc[1][1] += cv.y * nv.y; acc[1][2] += cv.y * nv.z; acc[1][3] += cv.y * nv.w;
      acc[2][0] += cv.z * nv.x; acc[2][1] += cv.z * nv.y; acc[2][2] += cv.z * nv.z; acc[2][3] += cv.z * nv.w;
      acc[3][0] += cv.w * nv.x; acc[3][1] += cv.w * nv.y; acc[3][2] += cv.w * nv.z; acc[3][3] += cv.w * nv.w;
    }
    __syncthreads();
  }
#pragma unroll
  for (int i = 0; i < 4; i++) {
    int c = c0 + ty * 4 + i;
    float bias = pb[c];
    float4 val;
    val.x = acc[i][0] + bias; val.y = acc[i][1] + bias;
    val.z = acc[i][2] + bias; val.w = acc[i][3] + bias;
    *(float4*)(out + ((size_t)b * Cc + c) * Nn + n0 + tx * 4) = val;
  }
}

// ---------------------------------------------------------------------------
extern "C" void kernel_launch(void* const* d_in, const int* in_sizes, int n_in,
                              void* d_out, int out_size, void* d_ws, size_t ws_size,
                              hipStream_t stream) {
  const float* x     = (const float*)d_in[0];
  const float* temp  = (const float*)d_in[1];
  const float* qkv_w = (const float*)d_in[2];
  const float* qkv_b = (const float*)d_in[3];
  const float* pw    = (const float*)d_in[4];
  const float* pb    = (const float*)d_in[5];
  float* out = (float*)d_out;

  float* qb = (float*)d_ws;          // [B][NH][N][HD]
  float* kb = qb + QSZ;
  float* vb = kb + QSZ;
  float* ob = vb + QSZ;              // [B][N][C]

  qkv_kernel<<<dim3(Nn / 64, C3 / 64, Bb), 256, 0, stream>>>(x, qkv_w, qkv_b, qb, kb, vb);
  norm_kernel<<<(2 * Bb * NH * Nn) / 16, 256, 0, stream>>>(qb, kb);
  attn_kernel<<<dim3(Nn / 128, NH, Bb), 128, 0, stream>>>(qb, kb, vb, temp, ob);
  proj_kernel<<<dim3(Nn / 64, Cc / 64, Bb), 256, 0, stream>>>(ob, pw, pb, out);
}

// Round 2
// 425.811 us; speedup vs baseline: 3.0897x; 3.0897x over previous
//
#include <hip/hip_runtime.h>
#include <hip/hip_bf16.h>

// Problem constants
#define Bb   16
#define Cc   384
#define Nn   1024
#define NH   8
#define HD   48
#define C3   1152
#define D64  64          // padded head dim for MFMA
#define KTS  72          // LDS row stride (ushorts) for K/V/P tiles: 64+8 pad

typedef short  bf16x8  __attribute__((ext_vector_type(8)));
typedef float  f32x4   __attribute__((ext_vector_type(4)));
typedef unsigned short ushort8 __attribute__((ext_vector_type(8)));

__device__ inline unsigned short f2bf(float f) {
  unsigned int u = __float_as_uint(f);
  unsigned int r = (u + 0x7FFFu + ((u >> 16) & 1u)) >> 16;
  return (unsigned short)r;
}
__device__ inline float bf2f(unsigned short s) {
  return __uint_as_float(((unsigned int)s) << 16);
}

// ---------------------------------------------------------------------------
// Kernel 1: QKV GEMM (fp32 compute, bf16 output).
// q,k -> [B][NH][N][64] (dims 48..63 filled later by norm kernel)
// v   -> [B][NH][N][48]
// ---------------------------------------------------------------------------
__global__ __launch_bounds__(256) void qkv_kernel(
    const float* __restrict__ x, const float* __restrict__ w,
    const float* __restrict__ bias,
    unsigned short* __restrict__ qh, unsigned short* __restrict__ kh,
    unsigned short* __restrict__ vb) {
  __shared__ float Wt[16][68];
  __shared__ float Xs[16][64];
  const int b  = blockIdx.z;
  const int j0 = blockIdx.y * 64;
  const int n0 = blockIdx.x * 64;
  const int tid = threadIdx.x;
  const int tx = tid & 15, ty = tid >> 4;
  const float* xb = x + (size_t)b * Cc * Nn;

  float acc[4][4] = {};
  for (int c0 = 0; c0 < Cc; c0 += 16) {
    {
      int r = tid >> 2, c4 = (tid & 3) * 4;
      float4 wv = *(const float4*)(w + (size_t)(j0 + r) * Cc + c0 + c4);
      Wt[c4 + 0][r] = wv.x; Wt[c4 + 1][r] = wv.y;
      Wt[c4 + 2][r] = wv.z; Wt[c4 + 3][r] = wv.w;
    }
    {
      int r = tid >> 4, n4 = (tid & 15) * 4;
      *(float4*)&Xs[r][n4] = *(const float4*)(xb + (size_t)(c0 + r) * Nn + n0 + n4);
    }
    __syncthreads();
#pragma unroll
    for (int kk = 0; kk < 16; kk++) {
      float4 wv = *(const float4*)&Wt[kk][ty * 4];
      float4 xv = *(const float4*)&Xs[kk][tx * 4];
      acc[0][0] += wv.x * xv.x; acc[0][1] += wv.x * xv.y; acc[0][2] += wv.x * xv.z; acc[0][3] += wv.x * xv.w;
      acc[1][0] += wv.y * xv.x; acc[1][1] += wv.y * xv.y; acc[1][2] += wv.y * xv.z; acc[1][3] += wv.y * xv.w;
      acc[2][0] += wv.z * xv.x; acc[2][1] += wv.z * xv.y; acc[2][2] += wv.z * xv.z; acc[2][3] += wv.z * xv.w;
      acc[3][0] += wv.w * xv.x; acc[3][1] += wv.w * xv.y; acc[3][2] += wv.w * xv.z; acc[3][3] += wv.w * xv.w;
    }
    __syncthreads();
  }

  const int jg0  = j0 + ty * 4;
  const int part = jg0 / Cc;
  const int rem  = jg0 % Cc;
  const int h    = rem / HD;
  const int d    = rem % HD;
  float4 bv = *(const float4*)(bias + jg0);
  unsigned short* dst = (part == 0) ? qh : (part == 1) ? kh : vb;
  const int stride = (part < 2) ? D64 : HD;
  unsigned short* base = dst + (size_t)(b * NH + h) * Nn * stride + d;
#pragma unroll
  for (int jj = 0; jj < 4; jj++) {
    int n = n0 + tx * 4 + jj;
    ushort4 sv;
    sv.x = f2bf(acc[0][jj] + bv.x); sv.y = f2bf(acc[1][jj] + bv.y);
    sv.z = f2bf(acc[2][jj] + bv.z); sv.w = f2bf(acc[3][jj] + bv.w);
    *(ushort4*)(base + (size_t)n * stride) = sv;
  }
}

// ---------------------------------------------------------------------------
// Kernel 2: in-place L2 norm of q,k rows (bf16) + zero the dim pads 48..63.
// 16 lanes/row x 3 dims.
// ---------------------------------------------------------------------------
__global__ __launch_bounds__(256) void normqk_kernel(
    unsigned short* __restrict__ qh, unsigned short* __restrict__ kh) {
  const int tid = threadIdx.x;
  const int row = blockIdx.x * 16 + (tid >> 4);
  const int l16 = tid & 15;
  const int TOT = Bb * NH * Nn;
  unsigned short* buf = (row < TOT) ? qh : kh;
  int r = (row < TOT) ? row : row - TOT;
  unsigned short* rowb = buf + (size_t)r * D64;
  unsigned short* p = rowb + l16 * 3;
  float a = bf2f(p[0]), b = bf2f(p[1]), c = bf2f(p[2]);
  float ss = a * a + b * b + c * c;
  ss += __shfl_xor(ss, 1, 16);
  ss += __shfl_xor(ss, 2, 16);
  ss += __shfl_xor(ss, 4, 16);
  ss += __shfl_xor(ss, 8, 16);
  float scale = 1.0f / fmaxf(sqrtf(ss), 1e-12f);
  p[0] = f2bf(a * scale); p[1] = f2bf(b * scale); p[2] = f2bf(c * scale);
  if (l16 < 8) ((unsigned int*)(rowb + HD))[l16] = 0u;   // dims 48..63 = 0
}

// ---------------------------------------------------------------------------
// Kernel 3: V transpose to [B][NH][64][N] bf16; row 48 = 1.0 (softmax-denom
// ones column), rows 49..63 = 0.
// One block = one 256-key chunk of one head.
// ---------------------------------------------------------------------------
__global__ __launch_bounds__(256) void vtrans_kernel(
    const unsigned short* __restrict__ vb, unsigned short* __restrict__ vt) {
  __shared__ unsigned short tr[48 * 264];   // [dim][key], pad 264
  const int tid = threadIdx.x;
  const int bh = blockIdx.x >> 2;
  const int k0 = (blockIdx.x & 3) * 256;
  const unsigned short* src = vb + (size_t)bh * Nn * HD + (size_t)k0 * HD;
  unsigned short* dst = vt + (size_t)bh * D64 * Nn + k0;

#pragma unroll
  for (int i = 0; i < 6; i++) {
    int idx8 = i * 256 + tid;           // 1536 ushort8 chunks = 256 keys x 48
    int key = idx8 / 6, dc = (idx8 % 6) * 8;
    ushort8 val = *(const ushort8*)(src + key * HD + dc);
#pragma unroll
    for (int j = 0; j < 8; j++) tr[(dc + j) * 264 + key] = val[j];
  }
  __syncthreads();
#pragma unroll
  for (int i = 0; i < 6; i++) {
    int c = i * 256 + tid;              // 48 rows x 32 chunks of 8
    int rw = c >> 5, off = (c & 31) * 8;
    ushort8 val = *(const ushort8*)(tr + rw * 264 + off);
    *(ushort8*)(dst + (size_t)rw * Nn + off) = val;
  }
  // ones row (48) and zero rows (49..63)
  if (tid < 32) {
    ushort8 ones;
#pragma unroll
    for (int j = 0; j < 8; j++) ones[j] = 0x3F80;
    *(ushort8*)(dst + (size_t)48 * Nn + tid * 8) = ones;
  }
#pragma unroll
  for (int i = 0; i < 2; i++) {
    int c = i * 256 + tid;
    if (c < 480) {
      int rw = 49 + (c >> 5), off = (c & 31) * 8;
      ushort8 z = {0, 0, 0, 0, 0, 0, 0, 0};
      *(ushort8*)(dst + (size_t)rw * Nn + off) = z;
    }
  }
}

// ---------------------------------------------------------------------------
// Kernel 4: MFMA flash attention.  Block = 4 waves, 64 q-rows (16/wave).
// Static softmax max M=|T| (q,k normalized => |s|<=1).  l computed via the
// ones column of V^T (O col 48 = sum of p).
// ---------------------------------------------------------------------------
__global__ __launch_bounds__(256) void attn_mfma(
    const unsigned short* __restrict__ qh, const unsigned short* __restrict__ kh,
    const unsigned short* __restrict__ vt, const float* __restrict__ temp,
    float* __restrict__ ob) {
  __shared__ unsigned short Kt[64 * KTS];       // [key][dim]
  __shared__ unsigned short Vt[64 * KTS];       // [dim][key]
  __shared__ unsigned short Pt[4 * 16 * KTS];   // per-wave [qrow][key]

  const int b = blockIdx.z, h = blockIdx.y;
  const int q0 = blockIdx.x * 64;
  const int tid = threadIdx.x;
  const int wave = tid >> 6, lane = tid & 63;
  const int quad = lane >> 4, l16 = lane & 15;

  const size_t headQ = ((size_t)(b * NH + h) * Nn) * D64;
  const unsigned short* Qg = qh + headQ + (size_t)(q0 + wave * 16) * D64;
  const unsigned short* Kg = kh + headQ;
  const unsigned short* Vg = vt + ((size_t)(b * NH + h) * D64) * Nn;

  // Q A-fragments (held in registers for whole kernel)
  bf16x8 qa0 = *(const bf16x8*)(Qg + l16 * D64 + quad * 8);
  bf16x8 qa1 = *(const bf16x8*)(Qg + l16 * D64 + quad * 8 + 32);

  const float T = temp[h];
  const float M = fabsf(T);

  f32x4 oacc[4];
#pragma unroll
  for (int g = 0; g < 4; g++) oacc[g] = (f32x4){0.f, 0.f, 0.f, 0.f};
  const f32x4 zf = (f32x4){0.f, 0.f, 0.f, 0.f};

  unsigned short* Ptw = Pt + wave * 16 * KTS;
  const int skey = tid >> 2;            // staging: key/dim row
  const int spart = (tid & 3) * 16;     // 16-ushort (32B) chunk

  for (int kt = 0; kt < Nn / 64; kt++) {
    __syncthreads();
    {  // stage K tile [64 key][64 dim] and V tile [64 dim][64 key]
      const unsigned short* ks = Kg + (size_t)(kt * 64 + skey) * D64 + spart;
      unsigned short* kd = Kt + skey * KTS + spart;
      *(uint4*)kd = *(const uint4*)ks;
      *(uint4*)(kd + 8) = *(const uint4*)(ks + 8);
      const unsigned short* vs = Vg + (size_t)skey * Nn + kt * 64 + spart;
      unsigned short* vd = Vt + skey * KTS + spart;
      *(uint4*)vd = *(const uint4*)vs;
      *(uint4*)(vd + 8) = *(const uint4*)(vs + 8);
    }
    __syncthreads();

    // S = Q K^T, p = exp(s*T - M) -> Pt (bf16)
#pragma unroll
    for (int g = 0; g < 4; g++) {
      const unsigned short* kb = Kt + (g * 16 + l16) * KTS + quad * 8;
      bf16x8 kf0 = *(const bf16x8*)kb;
      bf16x8 kf1 = *(const bf16x8*)(kb + 32);
      f32x4 s = __builtin_amdgcn_mfma_f32_16x16x32_bf16(qa0, kf0, zf, 0, 0, 0);
      s = __builtin_amdgcn_mfma_f32_16x16x32_bf16(qa1, kf1, s, 0, 0, 0);
#pragma unroll
      for (int r = 0; r < 4; r++) {
        float p = __expf(s[r] * T - M);
        Ptw[(quad * 4 + r) * KTS + g * 16 + l16] = f2bf(p);
      }
    }

    // PV: O += P V   (A = P[16 x 64keys], B = V^T tile)
    bf16x8 pa0 = *(const bf16x8*)(Ptw + l16 * KTS + quad * 8);
    bf16x8 pa1 = *(const bf16x8*)(Ptw + l16 * KTS + quad * 8 + 32);
#pragma unroll
    for (int g = 0; g < 4; g++) {
      const unsigned short* vb0 = Vt + (g * 16 + l16) * KTS + quad * 8;
      bf16x8 vf0 = *(const bf16x8*)vb0;
      bf16x8 vf1 = *(const bf16x8*)(vb0 + 32);
      oacc[g] = __builtin_amdgcn_mfma_f32_16x16x32_bf16(pa0, vf0, oacc[g], 0, 0, 0);
      oacc[g] = __builtin_amdgcn_mfma_f32_16x16x32_bf16(pa1, vf1, oacc[g], 0, 0, 0);
    }
  }

  // epilogue: l = O[:,48] lives in tile g=3, col 0 (lanes l16==0)
  float inv[4];
#pragma unroll
  for (int r = 0; r < 4; r++) {
    float l = __shfl(oacc[3][r], lane & 48);
    inv[r] = 1.0f / l;
  }
  float* op = ob + ((size_t)b * Nn + q0 + wave * 16 + quad * 4) * Cc + h * HD;
#pragma unroll
  for (int g = 0; g < 3; g++) {
#pragma unroll
    for (int r = 0; r < 4; r++) {
      op[(size_t)r * Cc + g * 16 + l16] = oacc[g][r] * inv[r];
    }
  }
}

// ---------------------------------------------------------------------------
// Kernel 5: output projection (fp32, unchanged).
// ---------------------------------------------------------------------------
__global__ __launch_bounds__(256) void proj_kernel(
    const float* __restrict__ ob, const float* __restrict__ pw,
    const float* __restrict__ pb, float* __restrict__ out) {
  __shared__ float Pt2[16][68];
  __shared__ float At[16][68];
  const int b  = blockIdx.z;
  const int c0 = blockIdx.y * 64;
  const int n0 = blockIdx.x * 64;
  const int tid = threadIdx.x;
  const int tx = tid & 15, ty = tid >> 4;

  float acc[4][4] = {};
  for (int j0 = 0; j0 < Cc; j0 += 16) {
    int r = tid >> 2, j4 = (tid & 3) * 4;
    {
      float4 pv = *(const float4*)(pw + (size_t)(c0 + r) * Cc + j0 + j4);
      Pt2[j4 + 0][r] = pv.x; Pt2[j4 + 1][r] = pv.y;
      Pt2[j4 + 2][r] = pv.z; Pt2[j4 + 3][r] = pv.w;
    }
    {
      float4 av = *(const float4*)(ob + ((size_t)b * Nn + n0 + r) * Cc + j0 + j4);
      At[j4 + 0][r] = av.x; At[j4 + 1][r] = av.y;
      At[j4 + 2][r] = av.z; At[j4 + 3][r] = av.w;
    }
    __syncthreads();
#pragma unroll
    for (int kk = 0; kk < 16; kk++) {
      float4 cv = *(const float4*)&Pt2[kk][ty * 4];
      float4 nv = *(const float4*)&At[kk][tx * 4];
      acc[0][0] += cv.x * nv.x; acc[0][1] += cv.x * nv.y; acc[0][2] += cv.x * nv.z; acc[0][3] += cv.x * nv.w;
      acc[1][0] += cv.y * nv.x; acc[1][1] += cv.y * nv.y; acc[1][2] += cv.y * nv.z; acc[1][3] += cv.y * nv.w;
      acc[2][0] += cv.z * nv.x; acc[2][1] += cv.z * nv.y; acc[2][2] += cv.z * nv.z; acc[2][3] += cv.z * nv.w;
      acc[3][0] += cv.w * nv.x; acc[3][1] += cv.w * nv.y; acc[3][2] += cv.w * nv.z; acc[3][3] += cv.w * nv.w;
    }
    __syncthreads();
  }
#pragma unroll
  for (int i = 0; i < 4; i++) {
    int c = c0 + ty * 4 + i;
    float bias = pb[c];
    float4 val;
    val.x = acc[i][0] + bias; val.y = acc[i][1] + bias;
    val.z = acc[i][2] + bias; val.w = acc[i][3] + bias;
    *(float4*)(out + ((size_t)b * Cc + c) * Nn + n0 + tx * 4) = val;
  }
}

// ---------------------------------------------------------------------------
extern "C" void kernel_launch(void* const* d_in, const int* in_sizes, int n_in,
                              void* d_out, int out_size, void* d_ws, size_t ws_size,
                              hipStream_t stream) {
  const float* x     = (const float*)d_in[0];
  const float* temp  = (const float*)d_in[1];
  const float* qkv_w = (const float*)d_in[2];
  const float* qkv_b = (const float*)d_in[3];
  const float* pw    = (const float*)d_in[4];
  const float* pb    = (const float*)d_in[5];
  float* out = (float*)d_out;

  const size_t QKN = (size_t)Bb * NH * Nn * D64;   // 8,388,608 ushorts
  const size_t VN  = (size_t)Bb * NH * Nn * HD;    // 6,291,456 ushorts
  unsigned short* Qh   = (unsigned short*)d_ws;
  unsigned short* Kh   = Qh + QKN;
  unsigned short* vb16 = Kh + QKN;
  unsigned short* VhT  = vb16 + VN;
  float* ob = (float*)(VhT + QKN);                 // [B][N][C] fp32

  qkv_kernel<<<dim3(Nn / 64, C3 / 64, Bb), 256, 0, stream>>>(x, qkv_w, qkv_b, Qh, Kh, vb16);
  normqk_kernel<<<(2 * Bb * NH * Nn) / 16, 256, 0, stream>>>(Qh, Kh);
  vtrans_kernel<<<Bb * NH * 4, 256, 0, stream>>>(vb16, VhT);
  attn_mfma<<<dim3(Nn / 64, NH, Bb), 256, 0, stream>>>(Qh, Kh, VhT, temp, ob);
  proj_kernel<<<dim3(Nn / 64, Cc / 64, Bb), 256, 0, stream>>>(ob, pw, pb, out);
}

// Round 3
// 280.153 us; speedup vs baseline: 4.6961x; 1.5199x over previous
//
#include <hip/hip_runtime.h>
#include <hip/hip_bf16.h>

// Problem constants
#define Bb   16
#define Cc   384
#define Nn   1024
#define NH   8
#define HD   48
#define C3   1152
#define D64  64          // padded head dim for MFMA
#define KTS  72          // LDS row stride (ushorts): 64 + 8 pad

typedef short  bf16x8  __attribute__((ext_vector_type(8)));
typedef float  f32x4   __attribute__((ext_vector_type(4)));
typedef unsigned short ushort8 __attribute__((ext_vector_type(8)));

__device__ inline unsigned short f2bf(float f) {
  unsigned int u = __float_as_uint(f);
  unsigned int r = (u + 0x7FFFu + ((u >> 16) & 1u)) >> 16;
  return (unsigned short)r;
}
__device__ inline float bf2f(unsigned short s) {
  return __uint_as_float(((unsigned int)s) << 16);
}

// ---------------------------------------------------------------------------
// Kernel A: split weights into bf16 hi/lo pairs (elementwise).
// ---------------------------------------------------------------------------
__global__ __launch_bounds__(256) void wsplit_kernel(
    const float* __restrict__ w, unsigned short* __restrict__ wh,
    unsigned short* __restrict__ wl) {
  int i = blockIdx.x * 256 + threadIdx.x;
  float v = w[i];
  unsigned short hi = f2bf(v);
  wh[i] = hi;
  wl[i] = f2bf(v - bf2f(hi));
}

// ---------------------------------------------------------------------------
// Kernel B: x [B][C][N] fp32 -> xT [B][N][C] bf16 hi/lo (transpose + split).
// Block: 64(c) x 64(n) tile.
// ---------------------------------------------------------------------------
__global__ __launch_bounds__(256) void xsplit_kernel(
    const float* __restrict__ x, unsigned short* __restrict__ xh,
    unsigned short* __restrict__ xl) {
  __shared__ float tile[64][65];
  const int b  = blockIdx.z;
  const int c0 = blockIdx.y * 64;
  const int n0 = blockIdx.x * 64;
  const int t  = threadIdx.x;
  const int rl = t >> 2, sc = (t & 3) * 16;
  {
    const float* src = x + ((size_t)b * Cc + c0 + rl) * Nn + n0 + sc;
#pragma unroll
    for (int i = 0; i < 4; i++) {
      float4 v = *(const float4*)(src + i * 4);
      tile[rl][sc + i * 4 + 0] = v.x; tile[rl][sc + i * 4 + 1] = v.y;
      tile[rl][sc + i * 4 + 2] = v.z; tile[rl][sc + i * 4 + 3] = v.w;
    }
  }
  __syncthreads();
  {
    ushort8 h0, h1, l0, l1;
#pragma unroll
    for (int i = 0; i < 8; i++) {
      float v = tile[sc + i][rl];
      unsigned short hi = f2bf(v);
      h0[i] = hi; l0[i] = f2bf(v - bf2f(hi));
    }
#pragma unroll
    for (int i = 0; i < 8; i++) {
      float v = tile[sc + 8 + i][rl];
      unsigned short hi = f2bf(v);
      h1[i] = hi; l1[i] = f2bf(v - bf2f(hi));
    }
    size_t dst = ((size_t)b * Nn + n0 + rl) * Cc + c0 + sc;
    *(ushort8*)(xh + dst) = h0; *(ushort8*)(xh + dst + 8) = h1;
    *(ushort8*)(xl + dst) = l0; *(ushort8*)(xl + dst + 8) = l1;
  }
}

// ---------------------------------------------------------------------------
// Kernel C: QKV GEMM via bf16 MFMA, split-precision 3-term.
// out[j][n] = sum_c w[j][c]*x[c][n];  A = w' [1152][384], B = xT [b][n][c].
// Tile 128(j) x 128(n), K-chunk 64.  4 waves in 2x2, each 64x64 (4x4 frags).
// ---------------------------------------------------------------------------
__global__ __launch_bounds__(256) void qkv_mfma(
    const unsigned short* __restrict__ wh, const unsigned short* __restrict__ wl,
    const unsigned short* __restrict__ xh, const unsigned short* __restrict__ xl,
    const float* __restrict__ bias,
    unsigned short* __restrict__ qh, unsigned short* __restrict__ kh,
    unsigned short* __restrict__ vb) {
  __shared__ unsigned short Ash[128 * KTS], Asl[128 * KTS];
  __shared__ unsigned short Bsh[128 * KTS], Bsl[128 * KTS];
  const int b  = blockIdx.z;
  const int j0 = blockIdx.y * 128;
  const int n0 = blockIdx.x * 128;
  const int tid = threadIdx.x;
  const int wave = tid >> 6, lane = tid & 63;
  const int quad = lane >> 4, l16 = lane & 15;
  const int wm = (wave >> 1) * 64, wn = (wave & 1) * 64;

  f32x4 acc[4][4];
#pragma unroll
  for (int mi = 0; mi < 4; mi++)
#pragma unroll
    for (int ni = 0; ni < 4; ni++) acc[mi][ni] = (f32x4){0.f, 0.f, 0.f, 0.f};

  for (int c0 = 0; c0 < Cc; c0 += 64) {
    __syncthreads();
#pragma unroll
    for (int i = 0; i < 4; i++) {
      int cidx = i * 256 + tid;
      int row = cidx >> 3, c8 = (cidx & 7) * 8;
      size_t ga = (size_t)(j0 + row) * Cc + c0 + c8;
      *(ushort8*)&Ash[row * KTS + c8] = *(const ushort8*)(wh + ga);
      *(ushort8*)&Asl[row * KTS + c8] = *(const ushort8*)(wl + ga);
      size_t gb = ((size_t)b * Nn + n0 + row) * Cc + c0 + c8;
      *(ushort8*)&Bsh[row * KTS + c8] = *(const ushort8*)(xh + gb);
      *(ushort8*)&Bsl[row * KTS + c8] = *(const ushort8*)(xl + gb);
    }
    __syncthreads();
#pragma unroll
    for (int ks = 0; ks < 64; ks += 32) {
      bf16x8 ah[4], al[4], bh[4], bl[4];
#pragma unroll
      for (int mi = 0; mi < 4; mi++) {
        int base = (wm + mi * 16 + l16) * KTS + ks + quad * 8;
        ah[mi] = *(const bf16x8*)&Ash[base];
        al[mi] = *(const bf16x8*)&Asl[base];
      }
#pragma unroll
      for (int ni = 0; ni < 4; ni++) {
        int base = (wn + ni * 16 + l16) * KTS + ks + quad * 8;
        bh[ni] = *(const bf16x8*)&Bsh[base];
        bl[ni] = *(const bf16x8*)&Bsl[base];
      }
#pragma unroll
      for (int mi = 0; mi < 4; mi++)
#pragma unroll
        for (int ni = 0; ni < 4; ni++) {
          acc[mi][ni] = __builtin_amdgcn_mfma_f32_16x16x32_bf16(ah[mi], bh[ni], acc[mi][ni], 0, 0, 0);
          acc[mi][ni] = __builtin_amdgcn_mfma_f32_16x16x32_bf16(ah[mi], bl[ni], acc[mi][ni], 0, 0, 0);
          acc[mi][ni] = __builtin_amdgcn_mfma_f32_16x16x32_bf16(al[mi], bh[ni], acc[mi][ni], 0, 0, 0);
        }
    }
  }

  // epilogue: scatter to q/k [B][NH][N][64] or v [B][NH][N][48], bf16.
  const int part = (j0 >= 768) ? 2 : (j0 >= 384 ? 1 : 0);
  unsigned short* dstq = (part == 0) ? qh : kh;
#pragma unroll
  for (int mi = 0; mi < 4; mi++) {
#pragma unroll
    for (int r = 0; r < 4; r++) {
      int j = j0 + wm + mi * 16 + quad * 4 + r;
      int jl = j - part * Cc;
      int h = jl / HD, d = jl % HD;
      float bv = bias[j];
#pragma unroll
      for (int ni = 0; ni < 4; ni++) {
        int n = n0 + wn + ni * 16 + l16;
        float val = acc[mi][ni][r] + bv;
        if (part < 2)
          dstq[((size_t)(b * NH + h) * Nn + n) * D64 + d] = f2bf(val);
        else
          vb[((size_t)(b * NH + h) * Nn + n) * HD + d] = f2bf(val);
      }
    }
  }
}

// ---------------------------------------------------------------------------
// Kernel D: in-place L2 norm of q,k rows (bf16) + zero dim pads 48..63.
// ---------------------------------------------------------------------------
__global__ __launch_bounds__(256) void normqk_kernel(
    unsigned short* __restrict__ qh, unsigned short* __restrict__ kh) {
  const int tid = threadIdx.x;
  const int row = blockIdx.x * 16 + (tid >> 4);
  const int l16 = tid & 15;
  const int TOT = Bb * NH * Nn;
  unsigned short* buf = (row < TOT) ? qh : kh;
  int r = (row < TOT) ? row : row - TOT;
  unsigned short* rowb = buf + (size_t)r * D64;
  unsigned short* p = rowb + l16 * 3;
  float a = bf2f(p[0]), b = bf2f(p[1]), c = bf2f(p[2]);
  float ss = a * a + b * b + c * c;
  ss += __shfl_xor(ss, 1, 16);
  ss += __shfl_xor(ss, 2, 16);
  ss += __shfl_xor(ss, 4, 16);
  ss += __shfl_xor(ss, 8, 16);
  float scale = 1.0f / fmaxf(sqrtf(ss), 1e-12f);
  p[0] = f2bf(a * scale); p[1] = f2bf(b * scale); p[2] = f2bf(c * scale);
  if (l16 < 8) ((unsigned int*)(rowb + HD))[l16] = 0u;
}

// ---------------------------------------------------------------------------
// Kernel E: V transpose to [B][NH][64][N]; row 48 = ones, 49..63 = 0.
// ---------------------------------------------------------------------------
__global__ __launch_bounds__(256) void vtrans_kernel(
    const unsigned short* __restrict__ vb, unsigned short* __restrict__ vt) {
  __shared__ unsigned short tr[48 * 264];
  const int tid = threadIdx.x;
  const int bh = blockIdx.x >> 2;
  const int k0 = (blockIdx.x & 3) * 256;
  const unsigned short* src = vb + (size_t)bh * Nn * HD + (size_t)k0 * HD;
  unsigned short* dst = vt + (size_t)bh * D64 * Nn + k0;

#pragma unroll
  for (int i = 0; i < 6; i++) {
    int idx8 = i * 256 + tid;
    int key = idx8 / 6, dc = (idx8 % 6) * 8;
    ushort8 val = *(const ushort8*)(src + key * HD + dc);
#pragma unroll
    for (int j = 0; j < 8; j++) tr[(dc + j) * 264 + key] = val[j];
  }
  __syncthreads();
#pragma unroll
  for (int i = 0; i < 6; i++) {
    int c = i * 256 + tid;
    int rw = c >> 5, off = (c & 31) * 8;
    ushort8 val = *(const ushort8*)(tr + rw * 264 + off);
    *(ushort8*)(dst + (size_t)rw * Nn + off) = val;
  }
  if (tid < 32) {
    ushort8 ones;
#pragma unroll
    for (int j = 0; j < 8; j++) ones[j] = 0x3F80;
    *(ushort8*)(dst + (size_t)48 * Nn + tid * 8) = ones;
  }
#pragma unroll
  for (int i = 0; i < 2; i++) {
    int c = i * 256 + tid;
    if (c < 480) {
      int rw = 49 + (c >> 5), off = (c & 31) * 8;
      ushort8 z = {0, 0, 0, 0, 0, 0, 0, 0};
      *(ushort8*)(dst + (size_t)rw * Nn + off) = z;
    }
  }
}

// ---------------------------------------------------------------------------
// Kernel F: MFMA flash attention (static max M=|T|, ones-column denominator).
// Epilogue emits ob as bf16 hi/lo for the MFMA projection.
// ---------------------------------------------------------------------------
__global__ __launch_bounds__(256) void attn_mfma(
    const unsigned short* __restrict__ qh, const unsigned short* __restrict__ kh,
    const unsigned short* __restrict__ vt, const float* __restrict__ temp,
    unsigned short* __restrict__ obh, unsigned short* __restrict__ obl) {
  __shared__ unsigned short Kt[64 * KTS];
  __shared__ unsigned short Vt[64 * KTS];
  __shared__ unsigned short Pt[4 * 16 * KTS];

  const int b = blockIdx.z, h = blockIdx.y;
  const int q0 = blockIdx.x * 64;
  const int tid = threadIdx.x;
  const int wave = tid >> 6, lane = tid & 63;
  const int quad = lane >> 4, l16 = lane & 15;

  const size_t headQ = ((size_t)(b * NH + h) * Nn) * D64;
  const unsigned short* Qg = qh + headQ + (size_t)(q0 + wave * 16) * D64;
  const unsigned short* Kg = kh + headQ;
  const unsigned short* Vg = vt + ((size_t)(b * NH + h) * D64) * Nn;

  bf16x8 qa0 = *(const bf16x8*)(Qg + l16 * D64 + quad * 8);
  bf16x8 qa1 = *(const bf16x8*)(Qg + l16 * D64 + quad * 8 + 32);

  const float T = temp[h];
  const float M = fabsf(T);

  f32x4 oacc[4];
#pragma unroll
  for (int g = 0; g < 4; g++) oacc[g] = (f32x4){0.f, 0.f, 0.f, 0.f};
  const f32x4 zf = (f32x4){0.f, 0.f, 0.f, 0.f};

  unsigned short* Ptw = Pt + wave * 16 * KTS;
  const int skey = tid >> 2;
  const int spart = (tid & 3) * 16;

  for (int kt = 0; kt < Nn / 64; kt++) {
    __syncthreads();
    {
      const unsigned short* ks = Kg + (size_t)(kt * 64 + skey) * D64 + spart;
      unsigned short* kd = Kt + skey * KTS + spart;
      *(uint4*)kd = *(const uint4*)ks;
      *(uint4*)(kd + 8) = *(const uint4*)(ks + 8);
      const unsigned short* vs = Vg + (size_t)skey * Nn + kt * 64 + spart;
      unsigned short* vd = Vt + skey * KTS + spart;
      *(uint4*)vd = *(const uint4*)vs;
      *(uint4*)(vd + 8) = *(const uint4*)(vs + 8);
    }
    __syncthreads();

#pragma unroll
    for (int g = 0; g < 4; g++) {
      const unsigned short* kb = Kt + (g * 16 + l16) * KTS + quad * 8;
      bf16x8 kf0 = *(const bf16x8*)kb;
      bf16x8 kf1 = *(const bf16x8*)(kb + 32);
      f32x4 s = __builtin_amdgcn_mfma_f32_16x16x32_bf16(qa0, kf0, zf, 0, 0, 0);
      s = __builtin_amdgcn_mfma_f32_16x16x32_bf16(qa1, kf1, s, 0, 0, 0);
#pragma unroll
      for (int r = 0; r < 4; r++) {
        float p = __expf(s[r] * T - M);
        Ptw[(quad * 4 + r) * KTS + g * 16 + l16] = f2bf(p);
      }
    }

    bf16x8 pa0 = *(const bf16x8*)(Ptw + l16 * KTS + quad * 8);
    bf16x8 pa1 = *(const bf16x8*)(Ptw + l16 * KTS + quad * 8 + 32);
#pragma unroll
    for (int g = 0; g < 4; g++) {
      const unsigned short* vb0 = Vt + (g * 16 + l16) * KTS + quad * 8;
      bf16x8 vf0 = *(const bf16x8*)vb0;
      bf16x8 vf1 = *(const bf16x8*)(vb0 + 32);
      oacc[g] = __builtin_amdgcn_mfma_f32_16x16x32_bf16(pa0, vf0, oacc[g], 0, 0, 0);
      oacc[g] = __builtin_amdgcn_mfma_f32_16x16x32_bf16(pa1, vf1, oacc[g], 0, 0, 0);
    }
  }

  float inv[4];
#pragma unroll
  for (int r = 0; r < 4; r++) {
    float l = __shfl(oacc[3][r], lane & 48);
    inv[r] = 1.0f / l;
  }
  size_t obase = ((size_t)b * Nn + q0 + wave * 16 + quad * 4) * Cc + h * HD;
#pragma unroll
  for (int g = 0; g < 3; g++) {
#pragma unroll
    for (int r = 0; r < 4; r++) {
      float val = oacc[g][r] * inv[r];
      unsigned short hi = f2bf(val);
      obh[obase + (size_t)r * Cc + g * 16 + l16] = hi;
      obl[obase + (size_t)r * Cc + g * 16 + l16] = f2bf(val - bf2f(hi));
    }
  }
}

// ---------------------------------------------------------------------------
// Kernel G: projection GEMM via bf16 MFMA, split-precision 3-term.
// out[b][c][n] = sum_j pw[c][j]*ob[b][n][j] + pb[c], fp32 out.
// ---------------------------------------------------------------------------
__global__ __launch_bounds__(256) void proj_mfma(
    const unsigned short* __restrict__ pwh, const unsigned short* __restrict__ pwl,
    const unsigned short* __restrict__ obh, const unsigned short* __restrict__ obl,
    const float* __restrict__ pb, float* __restrict__ out) {
  __shared__ unsigned short Ash[128 * KTS], Asl[128 * KTS];
  __shared__ unsigned short Bsh[128 * KTS], Bsl[128 * KTS];
  const int b  = blockIdx.z;
  const int c0m = blockIdx.y * 128;
  const int n0 = blockIdx.x * 128;
  const int tid = threadIdx.x;
  const int wave = tid >> 6, lane = tid & 63;
  const int quad = lane >> 4, l16 = lane & 15;
  const int wm = (wave >> 1) * 64, wn = (wave & 1) * 64;

  f32x4 acc[4][4];
#pragma unroll
  for (int mi = 0; mi < 4; mi++)
#pragma unroll
    for (int ni = 0; ni < 4; ni++) acc[mi][ni] = (f32x4){0.f, 0.f, 0.f, 0.f};

  for (int j0 = 0; j0 < Cc; j0 += 64) {
    __syncthreads();
#pragma unroll
    for (int i = 0; i < 4; i++) {
      int cidx = i * 256 + tid;
      int row = cidx >> 3, c8 = (cidx & 7) * 8;
      size_t ga = (size_t)(c0m + row) * Cc + j0 + c8;
      *(ushort8*)&Ash[row * KTS + c8] = *(const ushort8*)(pwh + ga);
      *(ushort8*)&Asl[row * KTS + c8] = *(const ushort8*)(pwl + ga);
      size_t gb = ((size_t)b * Nn + n0 + row) * Cc + j0 + c8;
      *(ushort8*)&Bsh[row * KTS + c8] = *(const ushort8*)(obh + gb);
      *(ushort8*)&Bsl[row * KTS + c8] = *(const ushort8*)(obl + gb);
    }
    __syncthreads();
#pragma unroll
    for (int ks = 0; ks < 64; ks += 32) {
      bf16x8 ah[4], al[4], bh[4], bl[4];
#pragma unroll
      for (int mi = 0; mi < 4; mi++) {
        int base = (wm + mi * 16 + l16) * KTS + ks + quad * 8;
        ah[mi] = *(const bf16x8*)&Ash[base];
        al[mi] = *(const bf16x8*)&Asl[base];
      }
#pragma unroll
      for (int ni = 0; ni < 4; ni++) {
        int base = (wn + ni * 16 + l16) * KTS + ks + quad * 8;
        bh[ni] = *(const bf16x8*)&Bsh[base];
        bl[ni] = *(const bf16x8*)&Bsl[base];
      }
#pragma unroll
      for (int mi = 0; mi < 4; mi++)
#pragma unroll
        for (int ni = 0; ni < 4; ni++) {
          acc[mi][ni] = __builtin_amdgcn_mfma_f32_16x16x32_bf16(ah[mi], bh[ni], acc[mi][ni], 0, 0, 0);
          acc[mi][ni] = __builtin_amdgcn_mfma_f32_16x16x32_bf16(ah[mi], bl[ni], acc[mi][ni], 0, 0, 0);
          acc[mi][ni] = __builtin_amdgcn_mfma_f32_16x16x32_bf16(al[mi], bh[ni], acc[mi][ni], 0, 0, 0);
        }
    }
  }

#pragma unroll
  for (int mi = 0; mi < 4; mi++) {
#pragma unroll
    for (int r = 0; r < 4; r++) {
      int c = c0m + wm + mi * 16 + quad * 4 + r;
      float bv = pb[c];
#pragma unroll
      for (int ni = 0; ni < 4; ni++) {
        int n = n0 + wn + ni * 16 + l16;
        out[((size_t)b * Cc + c) * Nn + n] = acc[mi][ni][r] + bv;
      }
    }
  }
}

// ---------------------------------------------------------------------------
extern "C" void kernel_launch(void* const* d_in, const int* in_sizes, int n_in,
                              void* d_out, int out_size, void* d_ws, size_t ws_size,
                              hipStream_t stream) {
  const float* x     = (const float*)d_in[0];
  const float* temp  = (const float*)d_in[1];
  const float* qkv_w = (const float*)d_in[2];
  const float* qkv_b = (const float*)d_in[3];
  const float* pw    = (const float*)d_in[4];
  const float* pb    = (const float*)d_in[5];
  float* out = (float*)d_out;

  const size_t QKN = (size_t)Bb * NH * Nn * D64;   // 8,388,608
  const size_t VN  = (size_t)Bb * NH * Nn * HD;    // 6,291,456
  const size_t WQN = (size_t)C3 * Cc;              // 442,368
  const size_t PWN = (size_t)Cc * Cc;              // 147,456

  unsigned short* Qh  = (unsigned short*)d_ws;
  unsigned short* Kh  = Qh + QKN;
  unsigned short* Vb  = Kh + QKN;
  unsigned short* VhT = Vb + VN;
  unsigned short* Wqh = VhT + QKN;
  unsigned short* Wql = Wqh + WQN;
  unsigned short* Pwh = Wql + WQN;
  unsigned short* Pwl = Pwh + PWN;
  unsigned short* Xth = Pwl + PWN;     // aliased by obh after qkv_mfma
  unsigned short* Xtl = Xth + VN;      // aliased by obl
  unsigned short* Obh = Xth;
  unsigned short* Obl = Xtl;

  wsplit_kernel<<<WQN / 256, 256, 0, stream>>>(qkv_w, Wqh, Wql);
  wsplit_kernel<<<PWN / 256, 256, 0, stream>>>(pw, Pwh, Pwl);
  xsplit_kernel<<<dim3(Nn / 64, Cc / 64, Bb), 256, 0, stream>>>(x, Xth, Xtl);
  qkv_mfma<<<dim3(Nn / 128, C3 / 128, Bb), 256, 0, stream>>>(Wqh, Wql, Xth, Xtl, qkv_b, Qh, Kh, Vb);
  normqk_kernel<<<(2 * Bb * NH * Nn) / 16, 256, 0, stream>>>(Qh, Kh);
  vtrans_kernel<<<Bb * NH * 4, 256, 0, stream>>>(Vb, VhT);
  attn_mfma<<<dim3(Nn / 64, NH, Bb), 256, 0, stream>>>(Qh, Kh, VhT, temp, Obh, Obl);
  proj_mfma<<<dim3(Nn / 128, Cc / 128, Bb), 256, 0, stream>>>(Pwh, Pwl, Obh, Obl, pb, out);
}

// Round 4
// 266.350 us; speedup vs baseline: 4.9394x; 1.0518x over previous
//
#include <hip/hip_runtime.h>
#include <hip/hip_bf16.h>

// Problem constants
#define Bb   16
#define Cc   384
#define Nn   1024
#define NH   8
#define HD   48
#define C3   1152
#define D64  64          // padded head dim for MFMA
#define KTS  72          // LDS row stride (ushorts) for K/V/GEMM tiles
#define PSTR 76          // LDS row stride for P tile (38 dw: conflict-free quads)

typedef short  bf16x8  __attribute__((ext_vector_type(8)));
typedef float  f32x4   __attribute__((ext_vector_type(4)));
typedef unsigned short ushort8 __attribute__((ext_vector_type(8)));

__device__ inline unsigned short f2bf(float f) {
  unsigned int u = __float_as_uint(f);
  unsigned int r = (u + 0x7FFFu + ((u >> 16) & 1u)) >> 16;
  return (unsigned short)r;
}
__device__ inline float bf2f(unsigned short s) {
  return __uint_as_float(((unsigned int)s) << 16);
}

// ---------------------------------------------------------------------------
// Kernel A: split weights into bf16 hi/lo pairs.
// ---------------------------------------------------------------------------
__global__ __launch_bounds__(256) void wsplit_kernel(
    const float* __restrict__ w, unsigned short* __restrict__ wh,
    unsigned short* __restrict__ wl) {
  int i = blockIdx.x * 256 + threadIdx.x;
  float v = w[i];
  unsigned short hi = f2bf(v);
  wh[i] = hi;
  wl[i] = f2bf(v - bf2f(hi));
}

// ---------------------------------------------------------------------------
// Kernel B: x [B][C][N] fp32 -> xT [B][N][C] bf16 (hi only; 2-term GEMM
// keeps full weight precision, x at bf16 ~2^-9 rel err).
// ---------------------------------------------------------------------------
__global__ __launch_bounds__(256) void xsplit_kernel(
    const float* __restrict__ x, unsigned short* __restrict__ xh) {
  __shared__ float tile[64][65];
  const int b  = blockIdx.z;
  const int c0 = blockIdx.y * 64;
  const int n0 = blockIdx.x * 64;
  const int t  = threadIdx.x;
  const int rl = t >> 2, sc = (t & 3) * 16;
  {
    const float* src = x + ((size_t)b * Cc + c0 + rl) * Nn + n0 + sc;
#pragma unroll
    for (int i = 0; i < 4; i++) {
      float4 v = *(const float4*)(src + i * 4);
      tile[rl][sc + i * 4 + 0] = v.x; tile[rl][sc + i * 4 + 1] = v.y;
      tile[rl][sc + i * 4 + 2] = v.z; tile[rl][sc + i * 4 + 3] = v.w;
    }
  }
  __syncthreads();
  {
    ushort8 h0, h1;
#pragma unroll
    for (int i = 0; i < 8; i++) h0[i] = f2bf(tile[sc + i][rl]);
#pragma unroll
    for (int i = 0; i < 8; i++) h1[i] = f2bf(tile[sc + 8 + i][rl]);
    size_t dst = ((size_t)b * Nn + n0 + rl) * Cc + c0 + sc;
    *(ushort8*)(xh + dst) = h0; *(ushort8*)(xh + dst + 8) = h1;
  }
}

// ---------------------------------------------------------------------------
// Kernel C: QKV GEMM, bf16 MFMA, 2-term split (whi+wlo) x xhi.
// Tile 128(j) x 128(n), K-chunk 64.
// ---------------------------------------------------------------------------
__global__ __launch_bounds__(256) void qkv_mfma(
    const unsigned short* __restrict__ wh, const unsigned short* __restrict__ wl,
    const unsigned short* __restrict__ xh,
    const float* __restrict__ bias,
    unsigned short* __restrict__ qh, unsigned short* __restrict__ kh,
    unsigned short* __restrict__ vb) {
  __shared__ unsigned short Ash[128 * KTS], Asl[128 * KTS];
  __shared__ unsigned short Bsh[128 * KTS];
  const int b  = blockIdx.z;
  const int j0 = blockIdx.y * 128;
  const int n0 = blockIdx.x * 128;
  const int tid = threadIdx.x;
  const int wave = tid >> 6, lane = tid & 63;
  const int quad = lane >> 4, l16 = lane & 15;
  const int wm = (wave >> 1) * 64, wn = (wave & 1) * 64;

  f32x4 acc[4][4];
#pragma unroll
  for (int mi = 0; mi < 4; mi++)
#pragma unroll
    for (int ni = 0; ni < 4; ni++) acc[mi][ni] = (f32x4){0.f, 0.f, 0.f, 0.f};

  for (int c0 = 0; c0 < Cc; c0 += 64) {
    __syncthreads();
#pragma unroll
    for (int i = 0; i < 4; i++) {
      int cidx = i * 256 + tid;
      int row = cidx >> 3, c8 = (cidx & 7) * 8;
      size_t ga = (size_t)(j0 + row) * Cc + c0 + c8;
      *(ushort8*)&Ash[row * KTS + c8] = *(const ushort8*)(wh + ga);
      *(ushort8*)&Asl[row * KTS + c8] = *(const ushort8*)(wl + ga);
      size_t gb = ((size_t)b * Nn + n0 + row) * Cc + c0 + c8;
      *(ushort8*)&Bsh[row * KTS + c8] = *(const ushort8*)(xh + gb);
    }
    __syncthreads();
#pragma unroll
    for (int ks = 0; ks < 64; ks += 32) {
      bf16x8 ah[4], al[4], bh[4];
#pragma unroll
      for (int mi = 0; mi < 4; mi++) {
        int base = (wm + mi * 16 + l16) * KTS + ks + quad * 8;
        ah[mi] = *(const bf16x8*)&Ash[base];
        al[mi] = *(const bf16x8*)&Asl[base];
      }
#pragma unroll
      for (int ni = 0; ni < 4; ni++) {
        int base = (wn + ni * 16 + l16) * KTS + ks + quad * 8;
        bh[ni] = *(const bf16x8*)&Bsh[base];
      }
#pragma unroll
      for (int mi = 0; mi < 4; mi++)
#pragma unroll
        for (int ni = 0; ni < 4; ni++) {
          acc[mi][ni] = __builtin_amdgcn_mfma_f32_16x16x32_bf16(ah[mi], bh[ni], acc[mi][ni], 0, 0, 0);
          acc[mi][ni] = __builtin_amdgcn_mfma_f32_16x16x32_bf16(al[mi], bh[ni], acc[mi][ni], 0, 0, 0);
        }
    }
  }

  const int part = (j0 >= 768) ? 2 : (j0 >= 384 ? 1 : 0);
  unsigned short* dstq = (part == 0) ? qh : kh;
#pragma unroll
  for (int mi = 0; mi < 4; mi++) {
#pragma unroll
    for (int r = 0; r < 4; r++) {
      int j = j0 + wm + mi * 16 + quad * 4 + r;
      int jl = j - part * Cc;
      int h = jl / HD, d = jl % HD;
      float bv = bias[j];
#pragma unroll
      for (int ni = 0; ni < 4; ni++) {
        int n = n0 + wn + ni * 16 + l16;
        float val = acc[mi][ni][r] + bv;
        if (part < 2)
          dstq[((size_t)(b * NH + h) * Nn + n) * D64 + d] = f2bf(val);
        else
          vb[((size_t)(b * NH + h) * Nn + n) * HD + d] = f2bf(val);
      }
    }
  }
}

// ---------------------------------------------------------------------------
// Kernel D: in-place L2 norm of q,k rows + zero dim pads 48..63.
// ---------------------------------------------------------------------------
__global__ __launch_bounds__(256) void normqk_kernel(
    unsigned short* __restrict__ qh, unsigned short* __restrict__ kh) {
  const int tid = threadIdx.x;
  const int row = blockIdx.x * 16 + (tid >> 4);
  const int l16 = tid & 15;
  const int TOT = Bb * NH * Nn;
  unsigned short* buf = (row < TOT) ? qh : kh;
  int r = (row < TOT) ? row : row - TOT;
  unsigned short* rowb = buf + (size_t)r * D64;
  unsigned short* p = rowb + l16 * 3;
  float a = bf2f(p[0]), b = bf2f(p[1]), c = bf2f(p[2]);
  float ss = a * a + b * b + c * c;
  ss += __shfl_xor(ss, 1, 16);
  ss += __shfl_xor(ss, 2, 16);
  ss += __shfl_xor(ss, 4, 16);
  ss += __shfl_xor(ss, 8, 16);
  float scale = 1.0f / fmaxf(sqrtf(ss), 1e-12f);
  p[0] = f2bf(a * scale); p[1] = f2bf(b * scale); p[2] = f2bf(c * scale);
  if (l16 < 8) ((unsigned int*)(rowb + HD))[l16] = 0u;
}

// ---------------------------------------------------------------------------
// Kernel E: V transpose to [B][NH][64][N]; row 48 = ones, 49..63 = 0.
// ---------------------------------------------------------------------------
__global__ __launch_bounds__(256) void vtrans_kernel(
    const unsigned short* __restrict__ vb, unsigned short* __restrict__ vt) {
  __shared__ unsigned short tr[48 * 264];
  const int tid = threadIdx.x;
  const int bh = blockIdx.x >> 2;
  const int k0 = (blockIdx.x & 3) * 256;
  const unsigned short* src = vb + (size_t)bh * Nn * HD + (size_t)k0 * HD;
  unsigned short* dst = vt + (size_t)bh * D64 * Nn + k0;

#pragma unroll
  for (int i = 0; i < 6; i++) {
    int idx8 = i * 256 + tid;
    int key = idx8 / 6, dc = (idx8 % 6) * 8;
    ushort8 val = *(const ushort8*)(src + key * HD + dc);
#pragma unroll
    for (int j = 0; j < 8; j++) tr[(dc + j) * 264 + key] = val[j];
  }
  __syncthreads();
#pragma unroll
  for (int i = 0; i < 6; i++) {
    int c = i * 256 + tid;
    int rw = c >> 5, off = (c & 31) * 8;
    ushort8 val = *(const ushort8*)(tr + rw * 264 + off);
    *(ushort8*)(dst + (size_t)rw * Nn + off) = val;
  }
  if (tid < 32) {
    ushort8 ones;
#pragma unroll
    for (int j = 0; j < 8; j++) ones[j] = 0x3F80;
    *(ushort8*)(dst + (size_t)48 * Nn + tid * 8) = ones;
  }
#pragma unroll
  for (int i = 0; i < 2; i++) {
    int c = i * 256 + tid;
    if (c < 480) {
      int rw = 49 + (c >> 5), off = (c & 31) * 8;
      ushort8 z = {0, 0, 0, 0, 0, 0, 0, 0};
      *(ushort8*)(dst + (size_t)rw * Nn + off) = z;
    }
  }
}

// ---------------------------------------------------------------------------
// Kernel F: MFMA flash attention.  4 waves x 32 q-rows = 128 q-rows/block.
// Static max M=|T|; denominator from ones-column of V^T.
// K/V frag reads shared across the 2 m-tiles per wave (halves LDS/MFMA).
// P rounded half-up (bias cancels in softmax ratio), stride 76 (conflict-free).
// ---------------------------------------------------------------------------
__global__ __launch_bounds__(256, 4) void attn_mfma(
    const unsigned short* __restrict__ qh, const unsigned short* __restrict__ kh,
    const unsigned short* __restrict__ vt, const float* __restrict__ temp,
    unsigned short* __restrict__ obh) {
  __shared__ unsigned short Kt[64 * KTS];
  __shared__ unsigned short Vt[64 * KTS];
  __shared__ unsigned short Pt[4 * 32 * PSTR];

  const int b = blockIdx.z, h = blockIdx.y;
  const int q0 = blockIdx.x * 128;
  const int tid = threadIdx.x;
  const int wave = tid >> 6, lane = tid & 63;
  const int quad = lane >> 4, l16 = lane & 15;

  const size_t headQ = ((size_t)(b * NH + h) * Nn) * D64;
  const unsigned short* Qg = qh + headQ + (size_t)(q0 + wave * 32) * D64;
  const unsigned short* Kg = kh + headQ;
  const unsigned short* Vg = vt + ((size_t)(b * NH + h) * D64) * Nn;

  bf16x8 qa0[2], qa1[2];
#pragma unroll
  for (int m = 0; m < 2; m++) {
    qa0[m] = *(const bf16x8*)(Qg + (m * 16 + l16) * D64 + quad * 8);
    qa1[m] = *(const bf16x8*)(Qg + (m * 16 + l16) * D64 + quad * 8 + 32);
  }

  const float T2 = temp[h] * 1.44269504f;   // exp(x) = exp2(x*log2e)
  const float M2 = fabsf(T2);

  f32x4 oacc[2][4];
#pragma unroll
  for (int m = 0; m < 2; m++)
#pragma unroll
    for (int g = 0; g < 4; g++) oacc[m][g] = (f32x4){0.f, 0.f, 0.f, 0.f};
  const f32x4 zf = (f32x4){0.f, 0.f, 0.f, 0.f};

  unsigned short* Ptw = Pt + wave * 32 * PSTR;
  const int skey = tid >> 2;
  const int spart = (tid & 3) * 16;

  for (int kt = 0; kt < Nn / 64; kt++) {
    __syncthreads();
    {
      const unsigned short* ks = Kg + (size_t)(kt * 64 + skey) * D64 + spart;
      unsigned short* kd = Kt + skey * KTS + spart;
      *(uint4*)kd = *(const uint4*)ks;
      *(uint4*)(kd + 8) = *(const uint4*)(ks + 8);
      const unsigned short* vs = Vg + (size_t)skey * Nn + kt * 64 + spart;
      unsigned short* vd = Vt + skey * KTS + spart;
      *(uint4*)vd = *(const uint4*)vs;
      *(uint4*)(vd + 8) = *(const uint4*)(vs + 8);
    }
    __syncthreads();

    // S = Q K^T for both m-tiles; p = exp2(s*T2 - M2) -> Pt (bf16 half-up)
#pragma unroll
    for (int g = 0; g < 4; g++) {
      const unsigned short* kb = Kt + (g * 16 + l16) * KTS + quad * 8;
      bf16x8 kf0 = *(const bf16x8*)kb;
      bf16x8 kf1 = *(const bf16x8*)(kb + 32);
#pragma unroll
      for (int m = 0; m < 2; m++) {
        f32x4 s = __builtin_amdgcn_mfma_f32_16x16x32_bf16(qa0[m], kf0, zf, 0, 0, 0);
        s = __builtin_amdgcn_mfma_f32_16x16x32_bf16(qa1[m], kf1, s, 0, 0, 0);
#pragma unroll
        for (int r = 0; r < 4; r++) {
          float p = __builtin_amdgcn_exp2f(s[r] * T2 - M2);
          unsigned int u = __float_as_uint(p) + 0x8000u;
          Ptw[(m * 16 + quad * 4 + r) * PSTR + g * 16 + l16] = (unsigned short)(u >> 16);
        }
      }
    }

    // PV: O += P V (V frags shared across m)
    bf16x8 pa0[2], pa1[2];
#pragma unroll
    for (int m = 0; m < 2; m++) {
      pa0[m] = *(const bf16x8*)(Ptw + (m * 16 + l16) * PSTR + quad * 8);
      pa1[m] = *(const bf16x8*)(Ptw + (m * 16 + l16) * PSTR + quad * 8 + 32);
    }
#pragma unroll
    for (int g = 0; g < 4; g++) {
      const unsigned short* vb0 = Vt + (g * 16 + l16) * KTS + quad * 8;
      bf16x8 vf0 = *(const bf16x8*)vb0;
      bf16x8 vf1 = *(const bf16x8*)(vb0 + 32);
#pragma unroll
      for (int m = 0; m < 2; m++) {
        oacc[m][g] = __builtin_amdgcn_mfma_f32_16x16x32_bf16(pa0[m], vf0, oacc[m][g], 0, 0, 0);
        oacc[m][g] = __builtin_amdgcn_mfma_f32_16x16x32_bf16(pa1[m], vf1, oacc[m][g], 0, 0, 0);
      }
    }
  }

  // epilogue: l = O[:,48] (tile g=3, col 0 -> lane quad*16)
#pragma unroll
  for (int m = 0; m < 2; m++) {
    float inv[4];
#pragma unroll
    for (int r = 0; r < 4; r++) {
      float l = __shfl(oacc[m][3][r], lane & 48);
      inv[r] = 1.0f / l;
    }
    size_t obase = ((size_t)b * Nn + q0 + wave * 32 + m * 16 + quad * 4) * Cc + h * HD;
#pragma unroll
    for (int g = 0; g < 3; g++) {
#pragma unroll
      for (int r = 0; r < 4; r++) {
        obh[obase + (size_t)r * Cc + g * 16 + l16] = f2bf(oacc[m][g][r] * inv[r]);
      }
    }
  }
}

// ---------------------------------------------------------------------------
// Kernel G: projection GEMM, 2-term split (pwh+pwl) x obh, fp32 out.
// ---------------------------------------------------------------------------
__global__ __launch_bounds__(256) void proj_mfma(
    const unsigned short* __restrict__ pwh, const unsigned short* __restrict__ pwl,
    const unsigned short* __restrict__ obh,
    const float* __restrict__ pb, float* __restrict__ out) {
  __shared__ unsigned short Ash[128 * KTS], Asl[128 * KTS];
  __shared__ unsigned short Bsh[128 * KTS];
  const int b  = blockIdx.z;
  const int c0m = blockIdx.y * 128;
  const int n0 = blockIdx.x * 128;
  const int tid = threadIdx.x;
  const int wave = tid >> 6, lane = tid & 63;
  const int quad = lane >> 4, l16 = lane & 15;
  const int wm = (wave >> 1) * 64, wn = (wave & 1) * 64;

  f32x4 acc[4][4];
#pragma unroll
  for (int mi = 0; mi < 4; mi++)
#pragma unroll
    for (int ni = 0; ni < 4; ni++) acc[mi][ni] = (f32x4){0.f, 0.f, 0.f, 0.f};

  for (int j0 = 0; j0 < Cc; j0 += 64) {
    __syncthreads();
#pragma unroll
    for (int i = 0; i < 4; i++) {
      int cidx = i * 256 + tid;
      int row = cidx >> 3, c8 = (cidx & 7) * 8;
      size_t ga = (size_t)(c0m + row) * Cc + j0 + c8;
      *(ushort8*)&Ash[row * KTS + c8] = *(const ushort8*)(pwh + ga);
      *(ushort8*)&Asl[row * KTS + c8] = *(const ushort8*)(pwl + ga);
      size_t gb = ((size_t)b * Nn + n0 + row) * Cc + j0 + c8;
      *(ushort8*)&Bsh[row * KTS + c8] = *(const ushort8*)(obh + gb);
    }
    __syncthreads();
#pragma unroll
    for (int ks = 0; ks < 64; ks += 32) {
      bf16x8 ah[4], al[4], bh[4];
#pragma unroll
      for (int mi = 0; mi < 4; mi++) {
        int base = (wm + mi * 16 + l16) * KTS + ks + quad * 8;
        ah[mi] = *(const bf16x8*)&Ash[base];
        al[mi] = *(const bf16x8*)&Asl[base];
      }
#pragma unroll
      for (int ni = 0; ni < 4; ni++) {
        int base = (wn + ni * 16 + l16) * KTS + ks + quad * 8;
        bh[ni] = *(const bf16x8*)&Bsh[base];
      }
#pragma unroll
      for (int mi = 0; mi < 4; mi++)
#pragma unroll
        for (int ni = 0; ni < 4; ni++) {
          acc[mi][ni] = __builtin_amdgcn_mfma_f32_16x16x32_bf16(ah[mi], bh[ni], acc[mi][ni], 0, 0, 0);
          acc[mi][ni] = __builtin_amdgcn_mfma_f32_16x16x32_bf16(al[mi], bh[ni], acc[mi][ni], 0, 0, 0);
        }
    }
  }

#pragma unroll
  for (int mi = 0; mi < 4; mi++) {
#pragma unroll
    for (int r = 0; r < 4; r++) {
      int c = c0m + wm + mi * 16 + quad * 4 + r;
      float bv = pb[c];
#pragma unroll
      for (int ni = 0; ni < 4; ni++) {
        int n = n0 + wn + ni * 16 + l16;
        out[((size_t)b * Cc + c) * Nn + n] = acc[mi][ni][r] + bv;
      }
    }
  }
}

// ---------------------------------------------------------------------------
extern "C" void kernel_launch(void* const* d_in, const int* in_sizes, int n_in,
                              void* d_out, int out_size, void* d_ws, size_t ws_size,
                              hipStream_t stream) {
  const float* x     = (const float*)d_in[0];
  const float* temp  = (const float*)d_in[1];
  const float* qkv_w = (const float*)d_in[2];
  const float* qkv_b = (const float*)d_in[3];
  const float* pw    = (const float*)d_in[4];
  const float* pb    = (const float*)d_in[5];
  float* out = (float*)d_out;

  const size_t QKN = (size_t)Bb * NH * Nn * D64;   // 8,388,608
  const size_t VN  = (size_t)Bb * NH * Nn * HD;    // 6,291,456
  const size_t WQN = (size_t)C3 * Cc;              // 442,368
  const size_t PWN = (size_t)Cc * Cc;              // 147,456

  unsigned short* Qh  = (unsigned short*)d_ws;
  unsigned short* Kh  = Qh + QKN;
  unsigned short* Vb  = Kh + QKN;
  unsigned short* VhT = Vb + VN;
  unsigned short* Wqh = VhT + QKN;
  unsigned short* Wql = Wqh + WQN;
  unsigned short* Pwh = Wql + WQN;
  unsigned short* Pwl = Pwh + PWN;
  unsigned short* Xth = Pwl + PWN;     // aliased by Obh after qkv_mfma
  unsigned short* Obh = Xth;

  wsplit_kernel<<<WQN / 256, 256, 0, stream>>>(qkv_w, Wqh, Wql);
  wsplit_kernel<<<PWN / 256, 256, 0, stream>>>(pw, Pwh, Pwl);
  xsplit_kernel<<<dim3(Nn / 64, Cc / 64, Bb), 256, 0, stream>>>(x, Xth);
  qkv_mfma<<<dim3(Nn / 128, C3 / 128, Bb), 256, 0, stream>>>(Wqh, Wql, Xth, qkv_b, Qh, Kh, Vb);
  normqk_kernel<<<(2 * Bb * NH * Nn) / 16, 256, 0, stream>>>(Qh, Kh);
  vtrans_kernel<<<Bb * NH * 4, 256, 0, stream>>>(Vb, VhT);
  attn_mfma<<<dim3(Nn / 128, NH, Bb), 256, 0, stream>>>(Qh, Kh, VhT, temp, Obh);
  proj_mfma<<<dim3(Nn / 128, Cc / 128, Bb), 256, 0, stream>>>(Pwh, Pwl, Obh, pb, out);
}

// Round 5
// 225.915 us; speedup vs baseline: 5.8235x; 1.1790x over previous
//
#include <hip/hip_runtime.h>
#include <hip/hip_bf16.h>

// Problem constants
#define Bb   16
#define Cc   384
#define Nn   1024
#define NH   8
#define HD   48
#define C3   1152
#define D64  64          // padded head dim for MFMA
#define KTS  72          // LDS row stride (ushorts) for K/V/GEMM tiles
#define PSTR 72          // LDS row stride for P tile [qrow][key]

typedef short  bf16x8  __attribute__((ext_vector_type(8)));
typedef float  f32x4   __attribute__((ext_vector_type(4)));
typedef unsigned short ushort8 __attribute__((ext_vector_type(8)));

__device__ inline unsigned short f2bf(float f) {
  unsigned int u = __float_as_uint(f);
  unsigned int r = (u + 0x7FFFu + ((u >> 16) & 1u)) >> 16;
  return (unsigned short)r;
}
__device__ inline float bf2f(unsigned short s) {
  return __uint_as_float(((unsigned int)s) << 16);
}
// pack two floats to bf16 pair (half-up rounding; softmax-ratio invariant)
__device__ inline unsigned int packbf(float a, float b) {
  unsigned int ua = (__float_as_uint(a) + 0x8000u) >> 16;
  unsigned int ub = (__float_as_uint(b) + 0x8000u) & 0xFFFF0000u;
  return ua | ub;
}

// ---------------------------------------------------------------------------
// Kernel A: prep — split both weight matrices to bf16 hi/lo AND fill VhT
// pad rows (48 = ones for softmax denominator, 49..63 = zeros).
// grid = 1728 (qkv_w) + 576 (pw) + 1024 (VhT fill) = 3328 blocks.
// ---------------------------------------------------------------------------
__global__ __launch_bounds__(256) void prep_kernel(
    const float* __restrict__ qkv_w, const float* __restrict__ pw,
    unsigned short* __restrict__ wqh, unsigned short* __restrict__ wql,
    unsigned short* __restrict__ pwh, unsigned short* __restrict__ pwl,
    unsigned short* __restrict__ vt) {
  const int bid = blockIdx.x;
  if (bid < 1728) {
    int i = bid * 256 + threadIdx.x;
    float v = qkv_w[i];
    unsigned short hi = f2bf(v);
    wqh[i] = hi; wql[i] = f2bf(v - bf2f(hi));
  } else if (bid < 2304) {
    int i = (bid - 1728) * 256 + threadIdx.x;
    float v = pw[i];
    unsigned short hi = f2bf(v);
    pwh[i] = hi; pwl[i] = f2bf(v - bf2f(hi));
  } else {
    int idx8 = (bid - 2304) * 256 + threadIdx.x;   // 262144 ushort8 chunks
    int bh = idx8 >> 11;                            // 2048 chunks per head
    int rem = idx8 & 2047;
    int row = 48 + (rem >> 7);
    int col = (rem & 127) * 8;
    unsigned short fill = (row == 48) ? (unsigned short)0x3F80 : (unsigned short)0;
    ushort8 v;
#pragma unroll
    for (int j = 0; j < 8; j++) v[j] = fill;
    *(ushort8*)(vt + (size_t)bh * D64 * Nn + (size_t)row * Nn + col) = v;
  }
}

// ---------------------------------------------------------------------------
// Kernel B: x [B][C][N] fp32 -> xT [B][N][C] bf16.
// ---------------------------------------------------------------------------
__global__ __launch_bounds__(256) void xsplit_kernel(
    const float* __restrict__ x, unsigned short* __restrict__ xh) {
  __shared__ float tile[64][65];
  const int b  = blockIdx.z;
  const int c0 = blockIdx.y * 64;
  const int n0 = blockIdx.x * 64;
  const int t  = threadIdx.x;
  const int rl = t >> 2, sc = (t & 3) * 16;
  {
    const float* src = x + ((size_t)b * Cc + c0 + rl) * Nn + n0 + sc;
#pragma unroll
    for (int i = 0; i < 4; i++) {
      float4 v = *(const float4*)(src + i * 4);
      tile[rl][sc + i * 4 + 0] = v.x; tile[rl][sc + i * 4 + 1] = v.y;
      tile[rl][sc + i * 4 + 2] = v.z; tile[rl][sc + i * 4 + 3] = v.w;
    }
  }
  __syncthreads();
  {
    ushort8 h0, h1;
#pragma unroll
    for (int i = 0; i < 8; i++) h0[i] = f2bf(tile[sc + i][rl]);
#pragma unroll
    for (int i = 0; i < 8; i++) h1[i] = f2bf(tile[sc + 8 + i][rl]);
    size_t dst = ((size_t)b * Nn + n0 + rl) * Cc + c0 + sc;
    *(ushort8*)(xh + dst) = h0; *(ushort8*)(xh + dst + 8) = h1;
  }
}

// ---------------------------------------------------------------------------
// Kernel C: QKV GEMM, bf16 MFMA, 2-term split (whi+wlo) x xhi.
// q,k -> [B][NH][N][64]; v -> V^T [B][NH][64][N] directly (coalesced).
// ---------------------------------------------------------------------------
__global__ __launch_bounds__(256) void qkv_mfma(
    const unsigned short* __restrict__ wh, const unsigned short* __restrict__ wl,
    const unsigned short* __restrict__ xh,
    const float* __restrict__ bias,
    unsigned short* __restrict__ qh, unsigned short* __restrict__ kh,
    unsigned short* __restrict__ vt) {
  __shared__ unsigned short Ash[128 * KTS], Asl[128 * KTS];
  __shared__ unsigned short Bsh[128 * KTS];
  const int b  = blockIdx.z;
  const int j0 = blockIdx.y * 128;
  const int n0 = blockIdx.x * 128;
  const int tid = threadIdx.x;
  const int wave = tid >> 6, lane = tid & 63;
  const int quad = lane >> 4, l16 = lane & 15;
  const int wm = (wave >> 1) * 64, wn = (wave & 1) * 64;

  f32x4 acc[4][4];
#pragma unroll
  for (int mi = 0; mi < 4; mi++)
#pragma unroll
    for (int ni = 0; ni < 4; ni++) acc[mi][ni] = (f32x4){0.f, 0.f, 0.f, 0.f};

  for (int c0 = 0; c0 < Cc; c0 += 64) {
    __syncthreads();
#pragma unroll
    for (int i = 0; i < 4; i++) {
      int cidx = i * 256 + tid;
      int row = cidx >> 3, c8 = (cidx & 7) * 8;
      size_t ga = (size_t)(j0 + row) * Cc + c0 + c8;
      *(ushort8*)&Ash[row * KTS + c8] = *(const ushort8*)(wh + ga);
      *(ushort8*)&Asl[row * KTS + c8] = *(const ushort8*)(wl + ga);
      size_t gb = ((size_t)b * Nn + n0 + row) * Cc + c0 + c8;
      *(ushort8*)&Bsh[row * KTS + c8] = *(const ushort8*)(xh + gb);
    }
    __syncthreads();
#pragma unroll
    for (int ks = 0; ks < 64; ks += 32) {
      bf16x8 ah[4], al[4], bh[4];
#pragma unroll
      for (int mi = 0; mi < 4; mi++) {
        int base = (wm + mi * 16 + l16) * KTS + ks + quad * 8;
        ah[mi] = *(const bf16x8*)&Ash[base];
        al[mi] = *(const bf16x8*)&Asl[base];
      }
#pragma unroll
      for (int ni = 0; ni < 4; ni++) {
        int base = (wn + ni * 16 + l16) * KTS + ks + quad * 8;
        bh[ni] = *(const bf16x8*)&Bsh[base];
      }
#pragma unroll
      for (int mi = 0; mi < 4; mi++)
#pragma unroll
        for (int ni = 0; ni < 4; ni++) {
          acc[mi][ni] = __builtin_amdgcn_mfma_f32_16x16x32_bf16(ah[mi], bh[ni], acc[mi][ni], 0, 0, 0);
          acc[mi][ni] = __builtin_amdgcn_mfma_f32_16x16x32_bf16(al[mi], bh[ni], acc[mi][ni], 0, 0, 0);
        }
    }
  }

  const int part = (j0 >= 768) ? 2 : (j0 >= 384 ? 1 : 0);
  unsigned short* dstq = (part == 0) ? qh : kh;
#pragma unroll
  for (int mi = 0; mi < 4; mi++) {
#pragma unroll
    for (int r = 0; r < 4; r++) {
      int j = j0 + wm + mi * 16 + quad * 4 + r;
      int jl = j - part * Cc;
      int h = jl / HD, d = jl % HD;
      float bv = bias[j];
      if (part < 2) {
#pragma unroll
        for (int ni = 0; ni < 4; ni++) {
          int n = n0 + wn + ni * 16 + l16;
          dstq[((size_t)(b * NH + h) * Nn + n) * D64 + d] = f2bf(acc[mi][ni][r] + bv);
        }
      } else {
        // V^T [B][NH][64][N]: n is l16-contiguous -> coalesced
        unsigned short* vrow = vt + ((size_t)(b * NH + h) * D64 + d) * Nn;
#pragma unroll
        for (int ni = 0; ni < 4; ni++) {
          int n = n0 + wn + ni * 16 + l16;
          vrow[n] = f2bf(acc[mi][ni][r] + bv);
        }
      }
    }
  }
}

// ---------------------------------------------------------------------------
// Kernel D: in-place L2 norm of q,k rows + zero dim pads 48..63.
// ---------------------------------------------------------------------------
__global__ __launch_bounds__(256) void normqk_kernel(
    unsigned short* __restrict__ qh, unsigned short* __restrict__ kh) {
  const int tid = threadIdx.x;
  const int row = blockIdx.x * 16 + (tid >> 4);
  const int l16 = tid & 15;
  const int TOT = Bb * NH * Nn;
  unsigned short* buf = (row < TOT) ? qh : kh;
  int r = (row < TOT) ? row : row - TOT;
  unsigned short* rowb = buf + (size_t)r * D64;
  unsigned short* p = rowb + l16 * 3;
  float a = bf2f(p[0]), b = bf2f(p[1]), c = bf2f(p[2]);
  float ss = a * a + b * b + c * c;
  ss += __shfl_xor(ss, 1, 16);
  ss += __shfl_xor(ss, 2, 16);
  ss += __shfl_xor(ss, 4, 16);
  ss += __shfl_xor(ss, 8, 16);
  float scale = 1.0f / fmaxf(sqrtf(ss), 1e-12f);
  p[0] = f2bf(a * scale); p[1] = f2bf(b * scale); p[2] = f2bf(c * scale);
  if (l16 < 8) ((unsigned int*)(rowb + HD))[l16] = 0u;
}

// ---------------------------------------------------------------------------
// Kernel E: MFMA flash attention, transposed data path + SW pipeline.
//  - S^T = mfma(K-frag, Q-frag): lane holds 4 consecutive keys per q-row
//    -> P written as packed b64 into [qrow][key] LDS tile.
//  - O^T = mfma(V^T-frag, P-frag): epilogue packed ushort4, one inv/lane.
//  - K/V tile t+1 prefetched into VGPRs during compute of tile t.
//  - XCD swizzle: 8 q-blocks of one head land on the same XCD (L2 reuse).
// ---------------------------------------------------------------------------
__global__ __launch_bounds__(256, 4) void attn_mfma(
    const unsigned short* __restrict__ qh, const unsigned short* __restrict__ kh,
    const unsigned short* __restrict__ vt, const float* __restrict__ temp,
    unsigned short* __restrict__ obh) {
  __shared__ unsigned short Kt[64 * KTS];
  __shared__ unsigned short Vt[64 * KTS];
  __shared__ unsigned short Pt[4 * 32 * PSTR];

  const int bid = blockIdx.x;
  const int hb = bid & 127;              // head-group: same hb -> same XCD
  const int q0 = (bid >> 7) * 128;
  const int b = hb >> 3, h = hb & 7;
  const int tid = threadIdx.x;
  const int wave = tid >> 6, lane = tid & 63;
  const int quad = lane >> 4, l16 = lane & 15;

  const size_t headQ = ((size_t)(b * NH + h) * Nn) * D64;
  const unsigned short* Qg = qh + headQ + (size_t)(q0 + wave * 32) * D64;
  const unsigned short* Kg = kh + headQ;
  const unsigned short* Vg = vt + ((size_t)(b * NH + h) * D64) * Nn;

  bf16x8 qa0[2], qa1[2];
#pragma unroll
  for (int m = 0; m < 2; m++) {
    qa0[m] = *(const bf16x8*)(Qg + (m * 16 + l16) * D64 + quad * 8);
    qa1[m] = *(const bf16x8*)(Qg + (m * 16 + l16) * D64 + quad * 8 + 32);
  }

  const float T2 = temp[h] * 1.44269504f;
  const float M2 = fabsf(T2);

  f32x4 oacc[2][4];
#pragma unroll
  for (int m = 0; m < 2; m++)
#pragma unroll
    for (int g = 0; g < 4; g++) oacc[m][g] = (f32x4){0.f, 0.f, 0.f, 0.f};
  const f32x4 zf = (f32x4){0.f, 0.f, 0.f, 0.f};

  unsigned short* Ptw = Pt + wave * 32 * PSTR;
  const int skey = tid >> 2;             // staging row (key for K, dim for V)
  const int spart = (tid & 3) * 16;      // 16-ushort chunk within row

  const unsigned short* ksrc = Kg + (size_t)skey * D64 + spart;
  const unsigned short* vsrc = Vg + (size_t)skey * Nn + spart;
  unsigned short* kdst = Kt + skey * KTS + spart;
  unsigned short* vdst = Vt + skey * KTS + spart;

  // prefetch tile 0 into registers
  uint4 kr0 = *(const uint4*)(ksrc);
  uint4 kr1 = *(const uint4*)(ksrc + 8);
  uint4 vr0 = *(const uint4*)(vsrc);
  uint4 vr1 = *(const uint4*)(vsrc + 8);

  for (int kt = 0; kt < Nn / 64; kt++) {
    __syncthreads();
    *(uint4*)kdst = kr0;
    *(uint4*)(kdst + 8) = kr1;
    *(uint4*)vdst = vr0;
    *(uint4*)(vdst + 8) = vr1;
    __syncthreads();

    if (kt < Nn / 64 - 1) {   // issue next tile's loads before compute
      const unsigned short* kn = ksrc + (size_t)(kt + 1) * 64 * D64;
      const unsigned short* vn = vsrc + (size_t)(kt + 1) * 64;
      kr0 = *(const uint4*)kn;
      kr1 = *(const uint4*)(kn + 8);
      vr0 = *(const uint4*)vn;
      vr1 = *(const uint4*)(vn + 8);
    }

    // S^T = K Q^T : lane (quad,l16) holds keys g*16+quad*4+{0..3} of qrow l16
    f32x4 sT[2][4];
#pragma unroll
    for (int g = 0; g < 4; g++) {
      const unsigned short* kb = Kt + (g * 16 + l16) * KTS + quad * 8;
      bf16x8 kf0 = *(const bf16x8*)kb;
      bf16x8 kf1 = *(const bf16x8*)(kb + 32);
#pragma unroll
      for (int m = 0; m < 2; m++) {
        f32x4 s = __builtin_amdgcn_mfma_f32_16x16x32_bf16(kf0, qa0[m], zf, 0, 0, 0);
        sT[m][g] = __builtin_amdgcn_mfma_f32_16x16x32_bf16(kf1, qa1[m], s, 0, 0, 0);
      }
    }

    // p = exp2(s*T2 - M2), packed pairs -> P [qrow][key] via b64 writes
#pragma unroll
    for (int m = 0; m < 2; m++) {
#pragma unroll
      for (int g = 0; g < 4; g++) {
        uint2 pw;
        pw.x = packbf(__builtin_amdgcn_exp2f(sT[m][g][0] * T2 - M2),
                      __builtin_amdgcn_exp2f(sT[m][g][1] * T2 - M2));
        pw.y = packbf(__builtin_amdgcn_exp2f(sT[m][g][2] * T2 - M2),
                      __builtin_amdgcn_exp2f(sT[m][g][3] * T2 - M2));
        *(uint2*)(Ptw + (m * 16 + l16) * PSTR + g * 16 + quad * 4) = pw;
      }
    }

    // P fragments (B-operand): lane l16 = qrow, keys quad*8+j (+32)
    bf16x8 pa[2][2];
#pragma unroll
    for (int m = 0; m < 2; m++) {
      pa[m][0] = *(const bf16x8*)(Ptw + (m * 16 + l16) * PSTR + quad * 8);
      pa[m][1] = *(const bf16x8*)(Ptw + (m * 16 + l16) * PSTR + quad * 8 + 32);
    }

    // O^T += V^T P^T : A = V^T rows (dim), B = P rows (qrow)
#pragma unroll
    for (int g = 0; g < 4; g++) {
      const unsigned short* vb0 = Vt + (g * 16 + l16) * KTS + quad * 8;
      bf16x8 vf0 = *(const bf16x8*)vb0;
      bf16x8 vf1 = *(const bf16x8*)(vb0 + 32);
#pragma unroll
      for (int m = 0; m < 2; m++) {
        oacc[m][g] = __builtin_amdgcn_mfma_f32_16x16x32_bf16(vf0, pa[m][0], oacc[m][g], 0, 0, 0);
        oacc[m][g] = __builtin_amdgcn_mfma_f32_16x16x32_bf16(vf1, pa[m][1], oacc[m][g], 0, 0, 0);
      }
    }
  }

  // epilogue: O^T lane (quad,l16) = dims g*16+quad*4+r of qrow l16.
  // denominator (dim 48) = oacc[m][3][0] at quad 0, lane l16.
#pragma unroll
  for (int m = 0; m < 2; m++) {
    float inv = 1.0f / __shfl(oacc[m][3][0], l16);
    size_t obase = ((size_t)b * Nn + q0 + wave * 32 + m * 16 + l16) * Cc + h * HD;
#pragma unroll
    for (int g = 0; g < 3; g++) {
      ushort4 sv;
      sv.x = f2bf(oacc[m][g][0] * inv);
      sv.y = f2bf(oacc[m][g][1] * inv);
      sv.z = f2bf(oacc[m][g][2] * inv);
      sv.w = f2bf(oacc[m][g][3] * inv);
      *(ushort4*)(obh + obase + g * 16 + quad * 4) = sv;
    }
  }
}

// ---------------------------------------------------------------------------
// Kernel F: projection GEMM, 2-term split (pwh+pwl) x obh, fp32 out.
// ---------------------------------------------------------------------------
__global__ __launch_bounds__(256) void proj_mfma(
    const unsigned short* __restrict__ pwh, const unsigned short* __restrict__ pwl,
    const unsigned short* __restrict__ obh,
    const float* __restrict__ pb, float* __restrict__ out) {
  __shared__ unsigned short Ash[128 * KTS], Asl[128 * KTS];
  __shared__ unsigned short Bsh[128 * KTS];
  const int b  = blockIdx.z;
  const int c0m = blockIdx.y * 128;
  const int n0 = blockIdx.x * 128;
  const int tid = threadIdx.x;
  const int wave = tid >> 6, lane = tid & 63;
  const int quad = lane >> 4, l16 = lane & 15;
  const int wm = (wave >> 1) * 64, wn = (wave & 1) * 64;

  f32x4 acc[4][4];
#pragma unroll
  for (int mi = 0; mi < 4; mi++)
#pragma unroll
    for (int ni = 0; ni < 4; ni++) acc[mi][ni] = (f32x4){0.f, 0.f, 0.f, 0.f};

  for (int j0 = 0; j0 < Cc; j0 += 64) {
    __syncthreads();
#pragma unroll
    for (int i = 0; i < 4; i++) {
      int cidx = i * 256 + tid;
      int row = cidx >> 3, c8 = (cidx & 7) * 8;
      size_t ga = (size_t)(c0m + row) * Cc + j0 + c8;
      *(ushort8*)&Ash[row * KTS + c8] = *(const ushort8*)(pwh + ga);
      *(ushort8*)&Asl[row * KTS + c8] = *(const ushort8*)(pwl + ga);
      size_t gb = ((size_t)b * Nn + n0 + row) * Cc + j0 + c8;
      *(ushort8*)&Bsh[row * KTS + c8] = *(const ushort8*)(obh + gb);
    }
    __syncthreads();
#pragma unroll
    for (int ks = 0; ks < 64; ks += 32) {
      bf16x8 ah[4], al[4], bh[4];
#pragma unroll
      for (int mi = 0; mi < 4; mi++) {
        int base = (wm + mi * 16 + l16) * KTS + ks + quad * 8;
        ah[mi] = *(const bf16x8*)&Ash[base];
        al[mi] = *(const bf16x8*)&Asl[base];
      }
#pragma unroll
      for (int ni = 0; ni < 4; ni++) {
        int base = (wn + ni * 16 + l16) * KTS + ks + quad * 8;
        bh[ni] = *(const bf16x8*)&Bsh[base];
      }
#pragma unroll
      for (int mi = 0; mi < 4; mi++)
#pragma unroll
        for (int ni = 0; ni < 4; ni++) {
          acc[mi][ni] = __builtin_amdgcn_mfma_f32_16x16x32_bf16(ah[mi], bh[ni], acc[mi][ni], 0, 0, 0);
          acc[mi][ni] = __builtin_amdgcn_mfma_f32_16x16x32_bf16(al[mi], bh[ni], acc[mi][ni], 0, 0, 0);
        }
    }
  }

#pragma unroll
  for (int mi = 0; mi < 4; mi++) {
#pragma unroll
    for (int r = 0; r < 4; r++) {
      int c = c0m + wm + mi * 16 + quad * 4 + r;
      float bv = pb[c];
#pragma unroll
      for (int ni = 0; ni < 4; ni++) {
        int n = n0 + wn + ni * 16 + l16;
        out[((size_t)b * Cc + c) * Nn + n] = acc[mi][ni][r] + bv;
      }
    }
  }
}

// ---------------------------------------------------------------------------
extern "C" void kernel_launch(void* const* d_in, const int* in_sizes, int n_in,
                              void* d_out, int out_size, void* d_ws, size_t ws_size,
                              hipStream_t stream) {
  const float* x     = (const float*)d_in[0];
  const float* temp  = (const float*)d_in[1];
  const float* qkv_w = (const float*)d_in[2];
  const float* qkv_b = (const float*)d_in[3];
  const float* pw    = (const float*)d_in[4];
  const float* pb    = (const float*)d_in[5];
  float* out = (float*)d_out;

  const size_t QKN = (size_t)Bb * NH * Nn * D64;   // 8,388,608
  const size_t VN  = (size_t)Bb * NH * Nn * HD;    // 6,291,456
  const size_t WQN = (size_t)C3 * Cc;              // 442,368
  const size_t PWN = (size_t)Cc * Cc;              // 147,456

  unsigned short* Qh  = (unsigned short*)d_ws;
  unsigned short* Kh  = Qh + QKN;
  unsigned short* VhT = Kh + QKN;                  // [B][NH][64][N]
  unsigned short* Wqh = VhT + QKN;
  unsigned short* Wql = Wqh + WQN;
  unsigned short* Pwh = Wql + WQN;
  unsigned short* Pwl = Pwh + PWN;
  unsigned short* Xth = Pwl + PWN;                 // aliased by Obh after qkv
  unsigned short* Obh = Xth;

  prep_kernel<<<3328, 256, 0, stream>>>(qkv_w, pw, Wqh, Wql, Pwh, Pwl, VhT);
  xsplit_kernel<<<dim3(Nn / 64, Cc / 64, Bb), 256, 0, stream>>>(x, Xth);
  qkv_mfma<<<dim3(Nn / 128, C3 / 128, Bb), 256, 0, stream>>>(Wqh, Wql, Xth, qkv_b, Qh, Kh, VhT);
  normqk_kernel<<<(2 * Bb * NH * Nn) / 16, 256, 0, stream>>>(Qh, Kh);
  attn_mfma<<<1024, 256, 0, stream>>>(Qh, Kh, VhT, temp, Obh);
  proj_mfma<<<dim3(Nn / 128, Cc / 128, Bb), 256, 0, stream>>>(Pwh, Pwl, Obh, pb, out);
}